// Round 3
// baseline (1614.363 us; speedup 1.0000x reference)
//
#include <hip/hip_runtime.h>
#include <hip/hip_bf16.h>

#define D 128

__device__ __forceinline__ void atomAddF(float* p, float v) {
#if defined(__HIP_PLATFORM_AMD__)
    unsafeAtomicAdd(p, v);   // native global_atomic_add_f32 on gfx90a+
#else
    atomicAdd(p, v);
#endif
}

// ---------------- column totals: total[d] = sum_n feat[n][d] ----------------
__global__ __launch_bounds__(128) void col_sum_kernel(const float* __restrict__ feat,
                                                      float* __restrict__ total, int n) {
    int d = threadIdx.x;  // 0..127
    float acc = 0.f;
    for (int r = blockIdx.x; r < n; r += gridDim.x)
        acc += feat[(size_t)r * D + d];
    atomAddF(&total[d], acc);
}

// ------- scatter: neigh[dst[e]][d] += feat[src[e]][d], 2 dims per thread -------
// work item i in [0, nE*64): e = i/64, dpair = i%64 -> dims {2*dpair, 2*dpair+1}
__global__ __launch_bounds__(256) void scatter_kernel(const float* __restrict__ feat,
                                                      const int* __restrict__ src,
                                                      const int* __restrict__ dst,
                                                      float* __restrict__ neigh, int nE) {
    long long nwork = (long long)nE * 64;
    long long stride = (long long)gridDim.x * 256;
    for (long long i = (long long)blockIdx.x * 256 + threadIdx.x; i < nwork; i += stride) {
        int e = (int)(i >> 6);
        int d2 = (int)(i & 63) * 2;
        int s = src[e];
        int t = dst[e];
        const float2 v = *(const float2*)&feat[(size_t)s * D + d2];
        float* p = &neigh[(size_t)t * D + d2];
        atomAddF(p + 0, v.x);
        atomAddF(p + 1, v.y);
    }
}

// ---------------- finalize: h = total - neigh; L2-normalize; out = hn @ W^T + b ----
// neigh aliases `out` (same buffer): each row is read and written by exactly one
// block (grid-stride over disjoint groups), reads precede writes with barriers.
__global__ __launch_bounds__(256) void finalize_kernel(const float* __restrict__ neigh,
                                                       const float* __restrict__ total,
                                                       const float* __restrict__ W,
                                                       const float* __restrict__ bias,
                                                       float* __restrict__ out,
                                                       int n, int ngroups) {
    __shared__ __hip_bfloat16 Wt[D * D];          // Wt[dd][j] = W[j][dd], 32 KB
    __shared__ __align__(16) float hnt[2][D][4];  // [half][dd][k]
    __shared__ float red[2][2][4];                // [half][wave_in_half][k]

    int tid = threadIdx.x;
    for (int idx = tid; idx < D * D; idx += 256) {
        int j = idx & 127, dd = idx >> 7;
        Wt[idx] = __float2bfloat16(W[(size_t)j * D + dd]);
    }
    int half = tid >> 7;
    int d    = tid & 127;
    int wih  = (tid >> 6) & 1;
    int lane = tid & 63;
    float bj  = bias[d];
    float tot = total[d];
    __syncthreads();

    for (int g = blockIdx.x; g < ngroups; g += gridDim.x) {
        int nb = g * 8 + half * 4;
        float h0 = 0.f, h1 = 0.f, h2 = 0.f, h3 = 0.f;
        if (nb + 0 < n) h0 = tot - neigh[(size_t)(nb + 0) * D + d];
        if (nb + 1 < n) h1 = tot - neigh[(size_t)(nb + 1) * D + d];
        if (nb + 2 < n) h2 = tot - neigh[(size_t)(nb + 2) * D + d];
        if (nb + 3 < n) h3 = tot - neigh[(size_t)(nb + 3) * D + d];

        float s0 = h0 * h0, s1 = h1 * h1, s2 = h2 * h2, s3 = h3 * h3;
        #pragma unroll
        for (int off = 32; off > 0; off >>= 1) {
            s0 += __shfl_xor(s0, off, 64);
            s1 += __shfl_xor(s1, off, 64);
            s2 += __shfl_xor(s2, off, 64);
            s3 += __shfl_xor(s3, off, 64);
        }
        if (lane == 0) {
            red[half][wih][0] = s0; red[half][wih][1] = s1;
            red[half][wih][2] = s2; red[half][wih][3] = s3;
        }
        __syncthreads();
        float rinv[4];
        #pragma unroll
        for (int k = 0; k < 4; ++k) {
            float nrm = sqrtf(red[half][0][k] + red[half][1][k]);
            rinv[k] = 1.0f / fmaxf(nrm, 1e-12f);
        }
        hnt[half][d][0] = h0 * rinv[0];
        hnt[half][d][1] = h1 * rinv[1];
        hnt[half][d][2] = h2 * rinv[2];
        hnt[half][d][3] = h3 * rinv[3];
        __syncthreads();

        float a0 = 0.f, a1 = 0.f, a2 = 0.f, a3 = 0.f;
        #pragma unroll 8
        for (int dd = 0; dd < D; ++dd) {
            float4 hn4 = *(const float4*)&hnt[half][dd][0];
            float w = __bfloat162float(Wt[dd * D + d]);
            a0 = fmaf(hn4.x, w, a0);
            a1 = fmaf(hn4.y, w, a1);
            a2 = fmaf(hn4.z, w, a2);
            a3 = fmaf(hn4.w, w, a3);
        }
        if (nb + 0 < n) out[(size_t)(nb + 0) * D + d] = a0 + bj;
        if (nb + 1 < n) out[(size_t)(nb + 1) * D + d] = a1 + bj;
        if (nb + 2 < n) out[(size_t)(nb + 2) * D + d] = a2 + bj;
        if (nb + 3 < n) out[(size_t)(nb + 3) * D + d] = a3 + bj;
        __syncthreads();
    }
}

extern "C" void kernel_launch(void* const* d_in, const int* in_sizes, int n_in,
                              void* d_out, int out_size, void* d_ws, size_t ws_size,
                              hipStream_t stream) {
    const float* feat = (const float*)d_in[0];
    const float* W    = (const float*)d_in[1];
    const float* bias = (const float*)d_in[2];
    const int*   src  = (const int*)d_in[3];
    const int*   dst  = (const int*)d_in[4];
    float* out = (float*)d_out;

    int n  = in_sizes[0] / D;   // 100000
    int nE = in_sizes[3];       // 1600000

    float* total = (float*)d_ws;       // 128 floats (512 B of ws)
    float* neigh = out;                // reuse d_out as the neigh_sum accumulator

    if (ws_size >= D * sizeof(float))
        hipMemsetAsync(d_ws, 0, D * sizeof(float), stream);
    hipMemsetAsync(neigh, 0, (size_t)out_size * sizeof(float), stream);

    col_sum_kernel<<<512, 128, 0, stream>>>(feat, total, n);

    scatter_kernel<<<16384, 256, 0, stream>>>(feat, src, dst, neigh, nE);

    int ngroups = (n + 7) / 8;
    finalize_kernel<<<2048, 256, 0, stream>>>(neigh, total, W, bias, out, n, ngroups);
}

// Round 4
// 851.928 us; speedup vs baseline: 1.8950x; 1.8950x over previous
//
#include <hip/hip_runtime.h>
#include <hip/hip_bf16.h>

#define D 128

__device__ __forceinline__ void atomAddF(float* p, float v) {
    unsafeAtomicAdd(p, v);   // native global_atomic_add_f32 on gfx90a+
}

// ---------------- column totals: total[d] = sum_n feat[n][d] ----------------
__global__ __launch_bounds__(128) void col_sum_kernel(const float* __restrict__ feat,
                                                      float* __restrict__ total, int n) {
    int d = threadIdx.x;  // 0..127
    float acc = 0.f;
    for (int r = blockIdx.x; r < n; r += gridDim.x)
        acc += feat[(size_t)r * D + d];
    atomAddF(&total[d], acc);
}

// ---------------- CSR build ----------------
__global__ __launch_bounds__(256) void hist_kernel(const int* __restrict__ dst,
                                                   int* __restrict__ deg, int nE) {
    int e = blockIdx.x * 256 + threadIdx.x;
    if (e < nE) atomicAdd(&deg[dst[e]], 1);
}

// single-block exclusive scan of deg[0..n) -> ptr[0..n] (ptr[0]=0) and cursor[i]=excl
__global__ __launch_bounds__(1024) void scan_kernel(const int* __restrict__ deg,
                                                    int* __restrict__ ptr,
                                                    int* __restrict__ cursor, int n) {
    __shared__ int wsum[16];
    __shared__ int s_carry;
    int tid = threadIdx.x, lane = tid & 63, w = tid >> 6;
    if (tid == 0) { s_carry = 0; ptr[0] = 0; }
    __syncthreads();
    for (int base = 0; base < n; base += 1024) {
        int i = base + tid;
        int v = (i < n) ? deg[i] : 0;
        int x = v;
        #pragma unroll
        for (int off = 1; off < 64; off <<= 1) {
            int y = __shfl_up(x, off, 64);
            if (lane >= off) x += y;
        }
        if (lane == 63) wsum[w] = x;
        __syncthreads();
        if (w == 0 && lane < 16) {
            int s = wsum[lane];
            #pragma unroll
            for (int off = 1; off < 16; off <<= 1) {
                int y = __shfl_up(s, off, 64);
                if (lane >= off) s += y;
            }
            wsum[lane] = s;
        }
        __syncthreads();
        int waveoff = (w == 0) ? 0 : wsum[w - 1];
        int incl = x + waveoff;          // inclusive within this 1024-chunk
        int carry = s_carry;
        if (i < n) {
            ptr[i + 1]  = carry + incl;
            cursor[i]   = carry + incl - v;
        }
        __syncthreads();                 // everyone read s_carry
        if (tid == 1023) s_carry = carry + incl;   // chunk total
        __syncthreads();
    }
}

__global__ __launch_bounds__(256) void fill_kernel(const int* __restrict__ src,
                                                   const int* __restrict__ dst,
                                                   int* __restrict__ cursor,
                                                   int* __restrict__ adj, int nE) {
    int e = blockIdx.x * 256 + threadIdx.x;
    if (e < nE) {
        int s = src[e], t = dst[e];
        int pos = atomicAdd(&cursor[t], 1);
        adj[pos] = s;
    }
}

// ---- fused: gather neigh-sum via CSR; h = total - sum; normalize; out = hn @ W^T + b ----
__global__ __launch_bounds__(256) void gather_finalize_kernel(const float* __restrict__ feat,
                                                              const int* __restrict__ ptr,
                                                              const int* __restrict__ adj,
                                                              const float* __restrict__ total,
                                                              const float* __restrict__ W,
                                                              const float* __restrict__ bias,
                                                              float* __restrict__ out,
                                                              int n, int ngroups) {
    __shared__ __hip_bfloat16 Wt[D * D];          // Wt[dd][j] = W[j][dd], 32 KB
    __shared__ __align__(16) float hnt[2][D][4];  // [half][dd][k]
    __shared__ float red[2][2][4];                // [half][wave_in_half][k]

    int tid = threadIdx.x;
    for (int idx = tid; idx < D * D; idx += 256) {
        int j = idx & 127, dd = idx >> 7;
        Wt[idx] = __float2bfloat16(W[(size_t)j * D + dd]);
    }
    int half = tid >> 7;
    int d    = tid & 127;
    int wih  = (tid >> 6) & 1;
    int lane = tid & 63;
    float bj  = bias[d];
    float tot = total[d];
    __syncthreads();

    for (int g = blockIdx.x; g < ngroups; g += gridDim.x) {
        int nb = g * 8 + half * 4;
        float h[4];
        #pragma unroll
        for (int k = 0; k < 4; ++k) {
            int v = nb + k;
            float hk = 0.f;
            if (v < n) {
                int p0 = ptr[v], p1 = ptr[v + 1];
                float acc = 0.f;
                int p = p0;
                for (; p + 1 < p1; p += 2) {
                    int s0 = adj[p], s1 = adj[p + 1];
                    acc += feat[(size_t)s0 * D + d];
                    acc += feat[(size_t)s1 * D + d];
                }
                if (p < p1) acc += feat[(size_t)adj[p] * D + d];
                hk = tot - acc;
            }
            h[k] = hk;
        }

        float s0 = h[0]*h[0], s1 = h[1]*h[1], s2 = h[2]*h[2], s3 = h[3]*h[3];
        #pragma unroll
        for (int off = 32; off > 0; off >>= 1) {
            s0 += __shfl_xor(s0, off, 64);
            s1 += __shfl_xor(s1, off, 64);
            s2 += __shfl_xor(s2, off, 64);
            s3 += __shfl_xor(s3, off, 64);
        }
        if (lane == 0) {
            red[half][wih][0] = s0; red[half][wih][1] = s1;
            red[half][wih][2] = s2; red[half][wih][3] = s3;
        }
        __syncthreads();
        float rinv[4];
        #pragma unroll
        for (int k = 0; k < 4; ++k) {
            float nrm = sqrtf(red[half][0][k] + red[half][1][k]);
            rinv[k] = 1.0f / fmaxf(nrm, 1e-12f);
        }
        hnt[half][d][0] = h[0] * rinv[0];
        hnt[half][d][1] = h[1] * rinv[1];
        hnt[half][d][2] = h[2] * rinv[2];
        hnt[half][d][3] = h[3] * rinv[3];
        __syncthreads();

        float a0 = 0.f, a1 = 0.f, a2 = 0.f, a3 = 0.f;
        #pragma unroll 8
        for (int dd = 0; dd < D; ++dd) {
            float4 hn4 = *(const float4*)&hnt[half][dd][0];
            float w = __bfloat162float(Wt[dd * D + d]);
            a0 = fmaf(hn4.x, w, a0);
            a1 = fmaf(hn4.y, w, a1);
            a2 = fmaf(hn4.z, w, a2);
            a3 = fmaf(hn4.w, w, a3);
        }
        if (nb + 0 < n) out[(size_t)(nb + 0) * D + d] = a0 + bj;
        if (nb + 1 < n) out[(size_t)(nb + 1) * D + d] = a1 + bj;
        if (nb + 2 < n) out[(size_t)(nb + 2) * D + d] = a2 + bj;
        if (nb + 3 < n) out[(size_t)(nb + 3) * D + d] = a3 + bj;
        __syncthreads();
    }
}

// ---------------- fallback path (round-3): atomic scatter + finalize ----------------
__global__ __launch_bounds__(256) void scatter_kernel(const float* __restrict__ feat,
                                                      const int* __restrict__ src,
                                                      const int* __restrict__ dst,
                                                      float* __restrict__ neigh, int nE) {
    long long nwork = (long long)nE * 64;
    long long stride = (long long)gridDim.x * 256;
    for (long long i = (long long)blockIdx.x * 256 + threadIdx.x; i < nwork; i += stride) {
        int e = (int)(i >> 6);
        int d2 = (int)(i & 63) * 2;
        int s = src[e];
        int t = dst[e];
        const float2 v = *(const float2*)&feat[(size_t)s * D + d2];
        float* p = &neigh[(size_t)t * D + d2];
        atomAddF(p + 0, v.x);
        atomAddF(p + 1, v.y);
    }
}

__global__ __launch_bounds__(256) void finalize_kernel(const float* __restrict__ neigh,
                                                       const float* __restrict__ total,
                                                       const float* __restrict__ W,
                                                       const float* __restrict__ bias,
                                                       float* __restrict__ out,
                                                       int n, int ngroups) {
    __shared__ __hip_bfloat16 Wt[D * D];
    __shared__ __align__(16) float hnt[2][D][4];
    __shared__ float red[2][2][4];

    int tid = threadIdx.x;
    for (int idx = tid; idx < D * D; idx += 256) {
        int j = idx & 127, dd = idx >> 7;
        Wt[idx] = __float2bfloat16(W[(size_t)j * D + dd]);
    }
    int half = tid >> 7;
    int d    = tid & 127;
    int wih  = (tid >> 6) & 1;
    int lane = tid & 63;
    float bj  = bias[d];
    float tot = total[d];
    __syncthreads();

    for (int g = blockIdx.x; g < ngroups; g += gridDim.x) {
        int nb = g * 8 + half * 4;
        float h0 = 0.f, h1 = 0.f, h2 = 0.f, h3 = 0.f;
        if (nb + 0 < n) h0 = tot - neigh[(size_t)(nb + 0) * D + d];
        if (nb + 1 < n) h1 = tot - neigh[(size_t)(nb + 1) * D + d];
        if (nb + 2 < n) h2 = tot - neigh[(size_t)(nb + 2) * D + d];
        if (nb + 3 < n) h3 = tot - neigh[(size_t)(nb + 3) * D + d];

        float s0 = h0*h0, s1 = h1*h1, s2 = h2*h2, s3 = h3*h3;
        #pragma unroll
        for (int off = 32; off > 0; off >>= 1) {
            s0 += __shfl_xor(s0, off, 64);
            s1 += __shfl_xor(s1, off, 64);
            s2 += __shfl_xor(s2, off, 64);
            s3 += __shfl_xor(s3, off, 64);
        }
        if (lane == 0) {
            red[half][wih][0] = s0; red[half][wih][1] = s1;
            red[half][wih][2] = s2; red[half][wih][3] = s3;
        }
        __syncthreads();
        float rinv[4];
        #pragma unroll
        for (int k = 0; k < 4; ++k) {
            float nrm = sqrtf(red[half][0][k] + red[half][1][k]);
            rinv[k] = 1.0f / fmaxf(nrm, 1e-12f);
        }
        hnt[half][d][0] = h0 * rinv[0];
        hnt[half][d][1] = h1 * rinv[1];
        hnt[half][d][2] = h2 * rinv[2];
        hnt[half][d][3] = h3 * rinv[3];
        __syncthreads();

        float a0 = 0.f, a1 = 0.f, a2 = 0.f, a3 = 0.f;
        #pragma unroll 8
        for (int dd = 0; dd < D; ++dd) {
            float4 hn4 = *(const float4*)&hnt[half][dd][0];
            float w = __bfloat162float(Wt[dd * D + d]);
            a0 = fmaf(hn4.x, w, a0);
            a1 = fmaf(hn4.y, w, a1);
            a2 = fmaf(hn4.z, w, a2);
            a3 = fmaf(hn4.w, w, a3);
        }
        if (nb + 0 < n) out[(size_t)(nb + 0) * D + d] = a0 + bj;
        if (nb + 1 < n) out[(size_t)(nb + 1) * D + d] = a1 + bj;
        if (nb + 2 < n) out[(size_t)(nb + 2) * D + d] = a2 + bj;
        if (nb + 3 < n) out[(size_t)(nb + 3) * D + d] = a3 + bj;
        __syncthreads();
    }
}

extern "C" void kernel_launch(void* const* d_in, const int* in_sizes, int n_in,
                              void* d_out, int out_size, void* d_ws, size_t ws_size,
                              hipStream_t stream) {
    const float* feat = (const float*)d_in[0];
    const float* W    = (const float*)d_in[1];
    const float* bias = (const float*)d_in[2];
    const int*   src  = (const int*)d_in[3];
    const int*   dst  = (const int*)d_in[4];
    float* out = (float*)d_out;

    int n  = in_sizes[0] / D;   // 100000
    int nE = in_sizes[3];       // 1600000

    // ws layout: [total: 128 f32][deg: n i32][cursor: n i32][ptr: n+1 i32][adj: nE i32]
    char* wsb = (char*)d_ws;
    float* total  = (float*)wsb;
    int*   deg    = (int*)(wsb + 512);
    int*   cursor = (int*)(wsb + 512 + (size_t)4 * n);
    int*   ptr    = (int*)(wsb + 512 + (size_t)8 * n);
    int*   adj    = (int*)(wsb + 512 + (size_t)12 * n + 4);
    size_t ws_needed = 512 + (size_t)12 * n + 4 + (size_t)4 * nE + 64;

    int ngroups = (n + 7) / 8;
    int eblocks = (nE + 255) / 256;

    if (ws_size >= ws_needed) {
        // zero total + deg
        hipMemsetAsync(d_ws, 0, 512 + (size_t)4 * n, stream);
        col_sum_kernel<<<512, 128, 0, stream>>>(feat, total, n);
        hist_kernel<<<eblocks, 256, 0, stream>>>(dst, deg, nE);
        scan_kernel<<<1, 1024, 0, stream>>>(deg, ptr, cursor, n);
        fill_kernel<<<eblocks, 256, 0, stream>>>(src, dst, cursor, adj, nE);
        gather_finalize_kernel<<<2048, 256, 0, stream>>>(feat, ptr, adj, total, W, bias,
                                                         out, n, ngroups);
    } else {
        // fallback: round-3 atomic-scatter path (neigh accumulates in d_out)
        float* neigh = out;
        if (ws_size >= D * sizeof(float))
            hipMemsetAsync(d_ws, 0, D * sizeof(float), stream);
        hipMemsetAsync(neigh, 0, (size_t)out_size * sizeof(float), stream);
        col_sum_kernel<<<512, 128, 0, stream>>>(feat, total, n);
        scatter_kernel<<<16384, 256, 0, stream>>>(feat, src, dst, neigh, nE);
        finalize_kernel<<<2048, 256, 0, stream>>>(neigh, total, W, bias, out, n, ngroups);
    }
}

// Round 5
// 472.528 us; speedup vs baseline: 3.4164x; 1.8029x over previous
//
#include <hip/hip_runtime.h>
#include <hip/hip_bf16.h>

#define D 128

typedef __bf16 bf16_t;
typedef bf16_t bf16x8 __attribute__((ext_vector_type(8)));
typedef float  f32x4  __attribute__((ext_vector_type(4)));

__device__ __forceinline__ void atomAddF(float* p, float v) {
    unsafeAtomicAdd(p, v);   // native global_atomic_add_f32 on gfx90a+
}

// ---------------- column totals: total[d] = sum_n feat[n][d] ----------------
__global__ __launch_bounds__(128) void col_sum_kernel(const float* __restrict__ feat,
                                                      float* __restrict__ total, int n) {
    int d = threadIdx.x;
    float acc = 0.f;
    for (int r = blockIdx.x; r < n; r += gridDim.x)
        acc += feat[(size_t)r * D + d];
    atomAddF(&total[d], acc);
}

// ---------------- fp32 -> bf16 feature staging ----------------
__global__ __launch_bounds__(256) void cvt_bf16_kernel(const float* __restrict__ feat,
                                                       bf16_t* __restrict__ featb,
                                                       long long n8) {
    long long i = (long long)blockIdx.x * 256 + threadIdx.x;
    if (i >= n8) return;
    const float4 a = *(const float4*)&feat[i * 8];
    const float4 b = *(const float4*)&feat[i * 8 + 4];
    bf16x8 o;
    o[0] = (bf16_t)a.x; o[1] = (bf16_t)a.y; o[2] = (bf16_t)a.z; o[3] = (bf16_t)a.w;
    o[4] = (bf16_t)b.x; o[5] = (bf16_t)b.y; o[6] = (bf16_t)b.z; o[7] = (bf16_t)b.w;
    *(bf16x8*)&featb[i * 8] = o;
}

// ---------------- CSR build ----------------
__global__ __launch_bounds__(256) void hist_kernel(const int* __restrict__ dst,
                                                   int* __restrict__ deg, int nE) {
    int e = blockIdx.x * 256 + threadIdx.x;
    if (e < nE) atomicAdd(&deg[dst[e]], 1);
}

// block b sums deg[b*1024 .. b*1024+1024) -> bsum[b]
__global__ __launch_bounds__(256) void scan_reduce_kernel(const int* __restrict__ deg,
                                                          int* __restrict__ bsum, int n) {
    int b = blockIdx.x, tid = threadIdx.x, lane = tid & 63, w = tid >> 6;
    int base = b * 1024 + tid * 4;
    int s = 0;
    #pragma unroll
    for (int j = 0; j < 4; ++j) { int i = base + j; if (i < n) s += deg[i]; }
    #pragma unroll
    for (int off = 32; off > 0; off >>= 1) s += __shfl_xor(s, off, 64);
    __shared__ int ws[4];
    if (lane == 0) ws[w] = s;
    __syncthreads();
    if (tid == 0) bsum[b] = ws[0] + ws[1] + ws[2] + ws[3];
}

// serial exclusive scan of bsum[0..nb) -> boff[0..nb)  (nb ~ 98, trivial)
__global__ void scan_bsum_kernel(const int* __restrict__ bsum,
                                 int* __restrict__ boff, int nb) {
    if (threadIdx.x == 0 && blockIdx.x == 0) {
        int acc = 0;
        for (int b = 0; b < nb; ++b) { boff[b] = acc; acc += bsum[b]; }
    }
}

// block b: exclusive scan of its 1024 degs + boff[b] -> cursor[i], ptr[i+1]
__global__ __launch_bounds__(256) void scan_apply_kernel(const int* __restrict__ deg,
                                                         const int* __restrict__ boff,
                                                         int* __restrict__ ptr,
                                                         int* __restrict__ cursor, int n) {
    int b = blockIdx.x, tid = threadIdx.x, lane = tid & 63, w = tid >> 6;
    int i0 = b * 1024 + tid * 4;
    int d[4];
    #pragma unroll
    for (int j = 0; j < 4; ++j) d[j] = (i0 + j < n) ? deg[i0 + j] : 0;
    int tsum = d[0] + d[1] + d[2] + d[3];
    int x = tsum;
    #pragma unroll
    for (int off = 1; off < 64; off <<= 1) {
        int y = __shfl_up(x, off, 64);
        if (lane >= off) x += y;
    }
    __shared__ int wsum[4];
    if (lane == 63) wsum[w] = x;
    __syncthreads();
    int wbase = 0;
    for (int k = 0; k < w; ++k) wbase += wsum[k];
    int e = boff[b] + wbase + x - tsum;   // exclusive prefix for item 0 of this thread
    #pragma unroll
    for (int j = 0; j < 4; ++j) {
        int i = i0 + j;
        if (i < n) { cursor[i] = e; ptr[i + 1] = e + d[j]; }
        e += d[j];
    }
    if (b == 0 && tid == 0) ptr[0] = 0;
}

__global__ __launch_bounds__(256) void fill_kernel(const int* __restrict__ src,
                                                   const int* __restrict__ dst,
                                                   int* __restrict__ cursor,
                                                   int* __restrict__ adj, int nE) {
    int e = blockIdx.x * 256 + threadIdx.x;
    if (e < nE) {
        int s = src[e], t = dst[e];
        int pos = atomicAdd(&cursor[t], 1);
        adj[pos] = s;
    }
}

// ---- fused: CSR gather (bf16, wide loads, LDS-staged indices) + normalize + MFMA GEMM ----
// 16 nodes per group. 256 threads: gather thread t -> node tid>>4, dims (tid&15)*8..+8.
// MFMA: wave w -> out cols w*32..w*32+31 (two 16x16 tiles), W fragments in registers.
__global__ __launch_bounds__(256, 4) void gather_mfma_kernel(const bf16_t* __restrict__ featb,
                                                             const int* __restrict__ ptr,
                                                             const int* __restrict__ adj,
                                                             const float* __restrict__ total,
                                                             const float* __restrict__ W,
                                                             const float* __restrict__ bias,
                                                             float* __restrict__ out,
                                                             int n, int ngroups) {
    __shared__ int    s_adj[1024];       // 4 KB
    __shared__ bf16_t s_hn[16][136];     // 4.25 KB, padded stride vs bank conflicts

    int tid  = threadIdx.x;
    int lane = tid & 63;
    int w    = tid >> 6;
    int quad = lane >> 4;
    int l16  = lane & 15;

    // ---- persistent per-block setup: W B-fragments + bias in registers ----
    // B[k][nc] for mfma_16x16x32: nc = lane&15, k = quad*8 + j   (k within 32-step)
    int n0 = w * 32;
    bf16x8 bfrag[4][2];
    #pragma unroll
    for (int s = 0; s < 4; ++s)
        #pragma unroll
        for (int c = 0; c < 2; ++c) {
            const float* wp = W + (size_t)(n0 + 16 * c + l16) * D + 32 * s + 8 * quad;
            float4 wa = *(const float4*)wp;
            float4 wb = *(const float4*)(wp + 4);
            bf16x8 bf;
            bf[0] = (bf16_t)wa.x; bf[1] = (bf16_t)wa.y; bf[2] = (bf16_t)wa.z; bf[3] = (bf16_t)wa.w;
            bf[4] = (bf16_t)wb.x; bf[5] = (bf16_t)wb.y; bf[6] = (bf16_t)wb.z; bf[7] = (bf16_t)wb.w;
            bfrag[s][c] = bf;
        }
    float bias0 = bias[n0 + l16];
    float bias1 = bias[n0 + 16 + l16];

    // gather-phase identity
    int k_node = tid >> 4;
    int d8 = (tid & 15) * 8;
    float tot8[8];
    {
        float4 ta = *(const float4*)&total[d8];
        float4 tb = *(const float4*)&total[d8 + 4];
        tot8[0] = ta.x; tot8[1] = ta.y; tot8[2] = ta.z; tot8[3] = ta.w;
        tot8[4] = tb.x; tot8[5] = tb.y; tot8[6] = tb.z; tot8[7] = tb.w;
    }

    for (int g = blockIdx.x; g < ngroups; g += gridDim.x) {
        int v0 = g * 16;
        int v  = v0 + k_node;
        bool valid = v < n;
        int p0 = valid ? ptr[v] : 0;
        int p1 = valid ? ptr[v + 1] : 0;
        int vend = v0 + 16 < n ? v0 + 16 : n;
        int P0 = ptr[v0];
        int P1 = ptr[vend];

        float acc8[8];
        #pragma unroll
        for (int e = 0; e < 8; ++e) acc8[e] = 0.f;

        for (int base = P0; base < P1; base += 1024) {
            int cnt = P1 - base; if (cnt > 1024) cnt = 1024;
            __syncthreads();
            for (int i = tid; i < cnt; i += 256) s_adj[i] = adj[base + i];
            __syncthreads();
            int lo = p0 > base ? p0 : base;
            int hi = p1 < base + cnt ? p1 : base + cnt;
            int p = lo;
            for (; p + 3 < hi; p += 4) {
                int s0 = s_adj[p - base],     s1 = s_adj[p - base + 1];
                int s2 = s_adj[p - base + 2], s3 = s_adj[p - base + 3];
                bf16x8 f0 = *(const bf16x8*)(featb + (size_t)s0 * D + d8);
                bf16x8 f1 = *(const bf16x8*)(featb + (size_t)s1 * D + d8);
                bf16x8 f2 = *(const bf16x8*)(featb + (size_t)s2 * D + d8);
                bf16x8 f3 = *(const bf16x8*)(featb + (size_t)s3 * D + d8);
                #pragma unroll
                for (int e = 0; e < 8; ++e)
                    acc8[e] += ((float)f0[e] + (float)f1[e]) + ((float)f2[e] + (float)f3[e]);
            }
            for (; p < hi; ++p) {
                int s0 = s_adj[p - base];
                bf16x8 f0 = *(const bf16x8*)(featb + (size_t)s0 * D + d8);
                #pragma unroll
                for (int e = 0; e < 8; ++e) acc8[e] += (float)f0[e];
            }
        }

        // h = total - neigh_sum (0 for padding rows); row L2 norm over the node's 16 threads
        float h8[8], ss = 0.f;
        #pragma unroll
        for (int e = 0; e < 8; ++e) {
            h8[e] = valid ? (tot8[e] - acc8[e]) : 0.f;
            ss = fmaf(h8[e], h8[e], ss);
        }
        ss += __shfl_xor(ss, 1, 64);
        ss += __shfl_xor(ss, 2, 64);
        ss += __shfl_xor(ss, 4, 64);
        ss += __shfl_xor(ss, 8, 64);
        float rinv = 1.0f / fmaxf(sqrtf(ss), 1e-12f);

        bf16x8 hv;
        #pragma unroll
        for (int e = 0; e < 8; ++e) hv[e] = (bf16_t)(h8[e] * rinv);
        *(bf16x8*)&s_hn[k_node][d8] = hv;
        __syncthreads();

        // MFMA: out[16 x 32-per-wave] = hn @ W^T; A[m][k]: m=lane&15, k=quad*8+j
        f32x4 acc0 = {0.f, 0.f, 0.f, 0.f};
        f32x4 acc1 = {0.f, 0.f, 0.f, 0.f};
        #pragma unroll
        for (int s = 0; s < 4; ++s) {
            bf16x8 a = *(const bf16x8*)&s_hn[l16][32 * s + 8 * quad];
            acc0 = __builtin_amdgcn_mfma_f32_16x16x32_bf16(a, bfrag[s][0], acc0, 0, 0, 0);
            acc1 = __builtin_amdgcn_mfma_f32_16x16x32_bf16(a, bfrag[s][1], acc1, 0, 0, 0);
        }
        // C/D: col = lane&15, row = quad*4 + reg
        #pragma unroll
        for (int r = 0; r < 4; ++r) {
            int row = quad * 4 + r;
            int vr = v0 + row;
            if (vr < n) {
                out[(size_t)vr * D + n0 + l16]      = acc0[r] + bias0;
                out[(size_t)vr * D + n0 + 16 + l16] = acc1[r] + bias1;
            }
        }
        __syncthreads();   // s_hn/s_adj reused next group
    }
}

// ---------------- fallback: round-4 fp32 CSR gather + VALU epilogue ----------------
__global__ __launch_bounds__(256) void gather_finalize_kernel(const float* __restrict__ feat,
                                                              const int* __restrict__ ptr,
                                                              const int* __restrict__ adj,
                                                              const float* __restrict__ total,
                                                              const float* __restrict__ W,
                                                              const float* __restrict__ bias,
                                                              float* __restrict__ out,
                                                              int n, int ngroups) {
    __shared__ __hip_bfloat16 Wt[D * D];
    __shared__ __align__(16) float hnt[2][D][4];
    __shared__ float red[2][2][4];

    int tid = threadIdx.x;
    for (int idx = tid; idx < D * D; idx += 256) {
        int j = idx & 127, dd = idx >> 7;
        Wt[idx] = __float2bfloat16(W[(size_t)j * D + dd]);
    }
    int half = tid >> 7, d = tid & 127, wih = (tid >> 6) & 1, lane = tid & 63;
    float bj = bias[d], tot = total[d];
    __syncthreads();

    for (int g = blockIdx.x; g < ngroups; g += gridDim.x) {
        int nb = g * 8 + half * 4;
        float h[4];
        #pragma unroll
        for (int k = 0; k < 4; ++k) {
            int v = nb + k;
            float hk = 0.f;
            if (v < n) {
                int p0 = ptr[v], p1 = ptr[v + 1];
                float acc = 0.f;
                int p = p0;
                for (; p + 1 < p1; p += 2) {
                    acc += feat[(size_t)adj[p] * D + d];
                    acc += feat[(size_t)adj[p + 1] * D + d];
                }
                if (p < p1) acc += feat[(size_t)adj[p] * D + d];
                hk = tot - acc;
            }
            h[k] = hk;
        }
        float s0 = h[0]*h[0], s1 = h[1]*h[1], s2 = h[2]*h[2], s3 = h[3]*h[3];
        #pragma unroll
        for (int off = 32; off > 0; off >>= 1) {
            s0 += __shfl_xor(s0, off, 64);
            s1 += __shfl_xor(s1, off, 64);
            s2 += __shfl_xor(s2, off, 64);
            s3 += __shfl_xor(s3, off, 64);
        }
        if (lane == 0) {
            red[half][wih][0] = s0; red[half][wih][1] = s1;
            red[half][wih][2] = s2; red[half][wih][3] = s3;
        }
        __syncthreads();
        float rinv[4];
        #pragma unroll
        for (int k = 0; k < 4; ++k)
            rinv[k] = 1.0f / fmaxf(sqrtf(red[half][0][k] + red[half][1][k]), 1e-12f);
        hnt[half][d][0] = h[0]*rinv[0]; hnt[half][d][1] = h[1]*rinv[1];
        hnt[half][d][2] = h[2]*rinv[2]; hnt[half][d][3] = h[3]*rinv[3];
        __syncthreads();
        float a0 = 0.f, a1 = 0.f, a2 = 0.f, a3 = 0.f;
        #pragma unroll 8
        for (int dd = 0; dd < D; ++dd) {
            float4 hn4 = *(const float4*)&hnt[half][dd][0];
            float wv = __bfloat162float(Wt[dd * D + d]);
            a0 = fmaf(hn4.x, wv, a0); a1 = fmaf(hn4.y, wv, a1);
            a2 = fmaf(hn4.z, wv, a2); a3 = fmaf(hn4.w, wv, a3);
        }
        if (nb + 0 < n) out[(size_t)(nb + 0) * D + d] = a0 + bj;
        if (nb + 1 < n) out[(size_t)(nb + 1) * D + d] = a1 + bj;
        if (nb + 2 < n) out[(size_t)(nb + 2) * D + d] = a2 + bj;
        if (nb + 3 < n) out[(size_t)(nb + 3) * D + d] = a3 + bj;
        __syncthreads();
    }
}

// last-resort fallback: atomic scatter into d_out
__global__ __launch_bounds__(256) void scatter_kernel(const float* __restrict__ feat,
                                                      const int* __restrict__ src,
                                                      const int* __restrict__ dst,
                                                      float* __restrict__ neigh, int nE) {
    long long nwork = (long long)nE * 64;
    long long stride = (long long)gridDim.x * 256;
    for (long long i = (long long)blockIdx.x * 256 + threadIdx.x; i < nwork; i += stride) {
        int e = (int)(i >> 6);
        int d2 = (int)(i & 63) * 2;
        int s = src[e], t = dst[e];
        const float2 vv = *(const float2*)&feat[(size_t)s * D + d2];
        float* p = &neigh[(size_t)t * D + d2];
        atomAddF(p + 0, vv.x);
        atomAddF(p + 1, vv.y);
    }
}

__global__ __launch_bounds__(256) void finalize_kernel(const float* __restrict__ neigh,
                                                       const float* __restrict__ total,
                                                       const float* __restrict__ W,
                                                       const float* __restrict__ bias,
                                                       float* __restrict__ out,
                                                       int n, int ngroups) {
    __shared__ __hip_bfloat16 Wt[D * D];
    __shared__ __align__(16) float hnt[2][D][4];
    __shared__ float red[2][2][4];
    int tid = threadIdx.x;
    for (int idx = tid; idx < D * D; idx += 256) {
        int j = idx & 127, dd = idx >> 7;
        Wt[idx] = __float2bfloat16(W[(size_t)j * D + dd]);
    }
    int half = tid >> 7, d = tid & 127, wih = (tid >> 6) & 1, lane = tid & 63;
    float bj = bias[d], tot = total[d];
    __syncthreads();
    for (int g = blockIdx.x; g < ngroups; g += gridDim.x) {
        int nb = g * 8 + half * 4;
        float h0=0,h1=0,h2=0,h3=0;
        if (nb+0 < n) h0 = tot - neigh[(size_t)(nb+0)*D + d];
        if (nb+1 < n) h1 = tot - neigh[(size_t)(nb+1)*D + d];
        if (nb+2 < n) h2 = tot - neigh[(size_t)(nb+2)*D + d];
        if (nb+3 < n) h3 = tot - neigh[(size_t)(nb+3)*D + d];
        float s0=h0*h0,s1=h1*h1,s2=h2*h2,s3=h3*h3;
        #pragma unroll
        for (int off = 32; off > 0; off >>= 1) {
            s0 += __shfl_xor(s0, off, 64); s1 += __shfl_xor(s1, off, 64);
            s2 += __shfl_xor(s2, off, 64); s3 += __shfl_xor(s3, off, 64);
        }
        if (lane == 0) { red[half][wih][0]=s0; red[half][wih][1]=s1; red[half][wih][2]=s2; red[half][wih][3]=s3; }
        __syncthreads();
        float rinv[4];
        #pragma unroll
        for (int k = 0; k < 4; ++k)
            rinv[k] = 1.0f / fmaxf(sqrtf(red[half][0][k] + red[half][1][k]), 1e-12f);
        hnt[half][d][0]=h0*rinv[0]; hnt[half][d][1]=h1*rinv[1];
        hnt[half][d][2]=h2*rinv[2]; hnt[half][d][3]=h3*rinv[3];
        __syncthreads();
        float a0=0,a1=0,a2=0,a3=0;
        #pragma unroll 8
        for (int dd = 0; dd < D; ++dd) {
            float4 hn4 = *(const float4*)&hnt[half][dd][0];
            float wv = __bfloat162float(Wt[dd * D + d]);
            a0 = fmaf(hn4.x, wv, a0); a1 = fmaf(hn4.y, wv, a1);
            a2 = fmaf(hn4.z, wv, a2); a3 = fmaf(hn4.w, wv, a3);
        }
        if (nb+0 < n) out[(size_t)(nb+0)*D + d] = a0 + bj;
        if (nb+1 < n) out[(size_t)(nb+1)*D + d] = a1 + bj;
        if (nb+2 < n) out[(size_t)(nb+2)*D + d] = a2 + bj;
        if (nb+3 < n) out[(size_t)(nb+3)*D + d] = a3 + bj;
        __syncthreads();
    }
}

static inline size_t align_up(size_t x, size_t a) { return (x + a - 1) & ~(a - 1); }

extern "C" void kernel_launch(void* const* d_in, const int* in_sizes, int n_in,
                              void* d_out, int out_size, void* d_ws, size_t ws_size,
                              hipStream_t stream) {
    const float* feat = (const float*)d_in[0];
    const float* W    = (const float*)d_in[1];
    const float* bias = (const float*)d_in[2];
    const int*   src  = (const int*)d_in[3];
    const int*   dst  = (const int*)d_in[4];
    float* out = (float*)d_out;

    int n  = in_sizes[0] / D;   // 100000
    int nE = in_sizes[3];       // 1600000

    // ws layout
    char* wsb = (char*)d_ws;
    size_t o_total = 0;
    size_t o_deg   = 512;
    size_t o_cur   = o_deg + (size_t)4 * n;
    size_t o_ptr   = o_cur + (size_t)4 * n;
    size_t o_bsum  = align_up(o_ptr + (size_t)4 * (n + 1), 512);
    size_t o_boff  = o_bsum + 1024;
    size_t o_adj   = o_boff + 1024;
    size_t o_featb = align_up(o_adj + (size_t)4 * nE, 512);
    size_t needB   = o_featb;                              // CSR, no bf16 staging
    size_t needA   = o_featb + (size_t)n * D * 2;          // + bf16 features

    float* total  = (float*)(wsb + o_total);
    int*   deg    = (int*)(wsb + o_deg);
    int*   cursor = (int*)(wsb + o_cur);
    int*   ptr    = (int*)(wsb + o_ptr);
    int*   bsum   = (int*)(wsb + o_bsum);
    int*   boff   = (int*)(wsb + o_boff);
    int*   adj    = (int*)(wsb + o_adj);
    bf16_t* featb = (bf16_t*)(wsb + o_featb);

    int eblocks = (nE + 255) / 256;
    int nb = (n + 1023) / 1024;            // scan blocks (98)

    if (ws_size >= needB) {
        hipMemsetAsync(wsb, 0, o_cur, stream);  // zero total + deg
        col_sum_kernel<<<512, 128, 0, stream>>>(feat, total, n);
        hist_kernel<<<eblocks, 256, 0, stream>>>(dst, deg, nE);
        scan_reduce_kernel<<<nb, 256, 0, stream>>>(deg, bsum, n);
        scan_bsum_kernel<<<1, 64, 0, stream>>>(bsum, boff, nb);
        scan_apply_kernel<<<nb, 256, 0, stream>>>(deg, boff, ptr, cursor, n);
        fill_kernel<<<eblocks, 256, 0, stream>>>(src, dst, cursor, adj, nE);
        if (ws_size >= needA) {
            long long n8 = (long long)n * (D / 8);
            int cblocks = (int)((n8 + 255) / 256);
            cvt_bf16_kernel<<<cblocks, 256, 0, stream>>>(feat, featb, n8);
            int ngroups = (n + 15) / 16;
            int grid = ngroups < 2048 ? ngroups : 2048;
            gather_mfma_kernel<<<grid, 256, 0, stream>>>(featb, ptr, adj, total, W, bias,
                                                         out, n, ngroups);
        } else {
            int ngroups = (n + 7) / 8;
            gather_finalize_kernel<<<2048, 256, 0, stream>>>(feat, ptr, adj, total, W, bias,
                                                             out, n, ngroups);
        }
    } else {
        float* neigh = out;
        if (ws_size >= D * sizeof(float))
            hipMemsetAsync(d_ws, 0, D * sizeof(float), stream);
        hipMemsetAsync(neigh, 0, (size_t)out_size * sizeof(float), stream);
        col_sum_kernel<<<512, 128, 0, stream>>>(feat, total, n);
        scatter_kernel<<<16384, 256, 0, stream>>>(feat, src, dst, neigh, nE);
        int ngroups = (n + 7) / 8;
        finalize_kernel<<<2048, 256, 0, stream>>>(neigh, total, W, bias, out, n, ngroups);
    }
}

// Round 6
// 362.632 us; speedup vs baseline: 4.4518x; 1.3030x over previous
//
#include <hip/hip_runtime.h>
#include <hip/hip_bf16.h>

#define D 128

typedef __bf16 bf16_t;
typedef bf16_t bf16x8 __attribute__((ext_vector_type(8)));
typedef float  f32x4  __attribute__((ext_vector_type(4)));

__device__ __forceinline__ void atomAddF(float* p, float v) {
    unsafeAtomicAdd(p, v);   // native global_atomic_add_f32 on gfx90a+
}

// ---------------- fused: fp32->bf16 staging + column totals ----------------
// chunk i = floats [i*8, i*8+8); col base = (i&15)*8 (invariant per thread).
__global__ __launch_bounds__(256) void cvt_colsum_kernel(const float* __restrict__ feat,
                                                         bf16_t* __restrict__ featb,
                                                         float* __restrict__ total,
                                                         long long n8) {
    __shared__ float red[4][16][8];
    int tid = threadIdx.x, lane = tid & 63, w = tid >> 6;
    long long G = (long long)gridDim.x * 256;
    float acc[8];
    #pragma unroll
    for (int e = 0; e < 8; ++e) acc[e] = 0.f;
    for (long long i = (long long)blockIdx.x * 256 + tid; i < n8; i += G) {
        const float4 a = *(const float4*)&feat[i * 8];
        const float4 b = *(const float4*)&feat[i * 8 + 4];
        bf16x8 o;
        o[0] = (bf16_t)a.x; o[1] = (bf16_t)a.y; o[2] = (bf16_t)a.z; o[3] = (bf16_t)a.w;
        o[4] = (bf16_t)b.x; o[5] = (bf16_t)b.y; o[6] = (bf16_t)b.z; o[7] = (bf16_t)b.w;
        *(bf16x8*)&featb[i * 8] = o;
        acc[0] += a.x; acc[1] += a.y; acc[2] += a.z; acc[3] += a.w;
        acc[4] += b.x; acc[5] += b.y; acc[6] += b.z; acc[7] += b.w;
    }
    // lanes l, l^16, l^32, l^48 share the same col base
    #pragma unroll
    for (int e = 0; e < 8; ++e) {
        acc[e] += __shfl_xor(acc[e], 16, 64);
        acc[e] += __shfl_xor(acc[e], 32, 64);
    }
    if (lane < 16) {
        #pragma unroll
        for (int e = 0; e < 8; ++e) red[w][lane][e] = acc[e];
    }
    __syncthreads();
    if (tid < 128) {
        int cb = tid >> 3, e = tid & 7;
        float s = red[0][cb][e] + red[1][cb][e] + red[2][cb][e] + red[3][cb][e];
        atomAddF(&total[cb * 8 + e], s);
    }
}

// ---------------- CSR build ----------------
__global__ __launch_bounds__(256) void hist_kernel(const int* __restrict__ dst,
                                                   int* __restrict__ deg, int nE) {
    int e = blockIdx.x * 256 + threadIdx.x;
    if (e < nE) atomicAdd(&deg[dst[e]], 1);
}

__global__ __launch_bounds__(256) void scan_reduce_kernel(const int* __restrict__ deg,
                                                          int* __restrict__ bsum, int n) {
    int b = blockIdx.x, tid = threadIdx.x, lane = tid & 63, w = tid >> 6;
    int base = b * 1024 + tid * 4;
    int s = 0;
    #pragma unroll
    for (int j = 0; j < 4; ++j) { int i = base + j; if (i < n) s += deg[i]; }
    #pragma unroll
    for (int off = 32; off > 0; off >>= 1) s += __shfl_xor(s, off, 64);
    __shared__ int ws[4];
    if (lane == 0) ws[w] = s;
    __syncthreads();
    if (tid == 0) bsum[b] = ws[0] + ws[1] + ws[2] + ws[3];
}

__global__ void scan_bsum_kernel(const int* __restrict__ bsum,
                                 int* __restrict__ boff, int nb) {
    if (threadIdx.x == 0 && blockIdx.x == 0) {
        int acc = 0;
        for (int b = 0; b < nb; ++b) { boff[b] = acc; acc += bsum[b]; }
    }
}

__global__ __launch_bounds__(256) void scan_apply_kernel(const int* __restrict__ deg,
                                                         const int* __restrict__ boff,
                                                         int* __restrict__ ptr,
                                                         int* __restrict__ cursor, int n) {
    int b = blockIdx.x, tid = threadIdx.x, lane = tid & 63, w = tid >> 6;
    int i0 = b * 1024 + tid * 4;
    int d[4];
    #pragma unroll
    for (int j = 0; j < 4; ++j) d[j] = (i0 + j < n) ? deg[i0 + j] : 0;
    int tsum = d[0] + d[1] + d[2] + d[3];
    int x = tsum;
    #pragma unroll
    for (int off = 1; off < 64; off <<= 1) {
        int y = __shfl_up(x, off, 64);
        if (lane >= off) x += y;
    }
    __shared__ int wsum[4];
    if (lane == 63) wsum[w] = x;
    __syncthreads();
    int wbase = 0;
    for (int k = 0; k < w; ++k) wbase += wsum[k];
    int e = boff[b] + wbase + x - tsum;
    #pragma unroll
    for (int j = 0; j < 4; ++j) {
        int i = i0 + j;
        if (i < n) { cursor[i] = e; ptr[i + 1] = e + d[j]; }
        e += d[j];
    }
    if (b == 0 && tid == 0) ptr[0] = 0;
}

// bcur[b] = ptr[min(b*1024, n)]  (bucket base offsets, free from node scan)
__global__ __launch_bounds__(256) void bcur_init_kernel(const int* __restrict__ ptr,
                                                        int* __restrict__ bcur,
                                                        int NB, int n) {
    int b = blockIdx.x * 256 + threadIdx.x;
    if (b < NB) {
        int i = b * 1024; if (i > n) i = n;
        bcur[b] = ptr[i];
    }
}

// per-block LDS hist -> reservation -> dense packed scatter (src|dlow in u32)
__global__ __launch_bounds__(256) void bucket_scatter_kernel(const int* __restrict__ src,
                                                             const int* __restrict__ dst,
                                                             int* __restrict__ bcur,
                                                             unsigned* __restrict__ packed,
                                                             int nE, int NB, int chunk) {
    __shared__ int hist[1024];
    __shared__ int cur[1024];
    int tid = threadIdx.x;
    int c0 = blockIdx.x * chunk;
    int c1 = c0 + chunk; if (c1 > nE) c1 = nE;
    for (int i = tid; i < NB; i += 256) hist[i] = 0;
    __syncthreads();
    for (int i = c0 + tid; i < c1; i += 256) atomicAdd(&hist[dst[i] >> 10], 1);
    __syncthreads();
    for (int i = tid; i < NB; i += 256) {
        int h = hist[i];
        cur[i] = h ? atomicAdd(&bcur[i], h) : 0;
    }
    __syncthreads();
    for (int i = c0 + tid; i < c1; i += 256) {
        int t = dst[i];
        int b = t >> 10;
        int off = atomicAdd(&cur[b], 1);
        packed[off] = ((unsigned)(t & 1023) << 17) | (unsigned)src[i];
    }
}

// per-bucket local fill: cursor span 4 KB, adj span ~64 KB -> L2-resident writes
__global__ __launch_bounds__(256) void fill_local_kernel(const unsigned* __restrict__ packed,
                                                         const int* __restrict__ ptr,
                                                         int* __restrict__ cursor,
                                                         int* __restrict__ adj,
                                                         int n, int nsub) {
    int b = blockIdx.x / nsub, q = blockIdx.x % nsub;
    int n0 = b * 1024;
    int n1 = n0 + 1024; if (n1 > n) n1 = n;
    if (n0 >= n) return;
    int P0 = ptr[n0], P1 = ptr[n1];
    long long len = P1 - P0;
    int c0 = P0 + (int)(len * q / nsub);
    int c1 = P0 + (int)(len * (q + 1) / nsub);
    for (int i = c0 + threadIdx.x; i < c1; i += 256) {
        unsigned v = packed[i];
        int s = (int)(v & 0x1FFFFu);
        int node = n0 + (int)(v >> 17);
        int pos = atomicAdd(&cursor[node], 1);
        adj[pos] = s;
    }
}

// ---- fused: CSR gather (bf16, wide loads, LDS-staged indices) + normalize + MFMA ----
__global__ __launch_bounds__(256, 4) void gather_mfma_kernel(const bf16_t* __restrict__ featb,
                                                             const int* __restrict__ ptr,
                                                             const int* __restrict__ adj,
                                                             const float* __restrict__ total,
                                                             const float* __restrict__ W,
                                                             const float* __restrict__ bias,
                                                             float* __restrict__ out,
                                                             int n, int ngroups) {
    __shared__ int    s_adj[1024];
    __shared__ bf16_t s_hn[16][136];

    int tid  = threadIdx.x;
    int lane = tid & 63;
    int w    = tid >> 6;
    int quad = lane >> 4;
    int l16  = lane & 15;

    int n0 = w * 32;
    bf16x8 bfrag[4][2];
    #pragma unroll
    for (int s = 0; s < 4; ++s)
        #pragma unroll
        for (int c = 0; c < 2; ++c) {
            const float* wp = W + (size_t)(n0 + 16 * c + l16) * D + 32 * s + 8 * quad;
            float4 wa = *(const float4*)wp;
            float4 wb = *(const float4*)(wp + 4);
            bf16x8 bf;
            bf[0] = (bf16_t)wa.x; bf[1] = (bf16_t)wa.y; bf[2] = (bf16_t)wa.z; bf[3] = (bf16_t)wa.w;
            bf[4] = (bf16_t)wb.x; bf[5] = (bf16_t)wb.y; bf[6] = (bf16_t)wb.z; bf[7] = (bf16_t)wb.w;
            bfrag[s][c] = bf;
        }
    float bias0 = bias[n0 + l16];
    float bias1 = bias[n0 + 16 + l16];

    int k_node = tid >> 4;
    int d8 = (tid & 15) * 8;
    float tot8[8];
    {
        float4 ta = *(const float4*)&total[d8];
        float4 tb = *(const float4*)&total[d8 + 4];
        tot8[0] = ta.x; tot8[1] = ta.y; tot8[2] = ta.z; tot8[3] = ta.w;
        tot8[4] = tb.x; tot8[5] = tb.y; tot8[6] = tb.z; tot8[7] = tb.w;
    }

    for (int g = blockIdx.x; g < ngroups; g += gridDim.x) {
        int v0 = g * 16;
        int v  = v0 + k_node;
        bool valid = v < n;
        int p0 = valid ? ptr[v] : 0;
        int p1 = valid ? ptr[v + 1] : 0;
        int vend = v0 + 16 < n ? v0 + 16 : n;
        int P0 = ptr[v0];
        int P1 = ptr[vend];

        float acc8[8];
        #pragma unroll
        for (int e = 0; e < 8; ++e) acc8[e] = 0.f;

        for (int base = P0; base < P1; base += 1024) {
            int cnt = P1 - base; if (cnt > 1024) cnt = 1024;
            __syncthreads();
            for (int i = tid; i < cnt; i += 256) s_adj[i] = adj[base + i];
            __syncthreads();
            int lo = p0 > base ? p0 : base;
            int hi = p1 < base + cnt ? p1 : base + cnt;
            int p = lo;
            for (; p + 3 < hi; p += 4) {
                int s0 = s_adj[p - base],     s1 = s_adj[p - base + 1];
                int s2 = s_adj[p - base + 2], s3 = s_adj[p - base + 3];
                bf16x8 f0 = *(const bf16x8*)(featb + (size_t)s0 * D + d8);
                bf16x8 f1 = *(const bf16x8*)(featb + (size_t)s1 * D + d8);
                bf16x8 f2 = *(const bf16x8*)(featb + (size_t)s2 * D + d8);
                bf16x8 f3 = *(const bf16x8*)(featb + (size_t)s3 * D + d8);
                #pragma unroll
                for (int e = 0; e < 8; ++e)
                    acc8[e] += ((float)f0[e] + (float)f1[e]) + ((float)f2[e] + (float)f3[e]);
            }
            for (; p < hi; ++p) {
                int s0 = s_adj[p - base];
                bf16x8 f0 = *(const bf16x8*)(featb + (size_t)s0 * D + d8);
                #pragma unroll
                for (int e = 0; e < 8; ++e) acc8[e] += (float)f0[e];
            }
        }

        float h8[8], ss = 0.f;
        #pragma unroll
        for (int e = 0; e < 8; ++e) {
            h8[e] = valid ? (tot8[e] - acc8[e]) : 0.f;
            ss = fmaf(h8[e], h8[e], ss);
        }
        ss += __shfl_xor(ss, 1, 64);
        ss += __shfl_xor(ss, 2, 64);
        ss += __shfl_xor(ss, 4, 64);
        ss += __shfl_xor(ss, 8, 64);
        float rinv = 1.0f / fmaxf(sqrtf(ss), 1e-12f);

        bf16x8 hv;
        #pragma unroll
        for (int e = 0; e < 8; ++e) hv[e] = (bf16_t)(h8[e] * rinv);
        *(bf16x8*)&s_hn[k_node][d8] = hv;
        __syncthreads();

        f32x4 acc0 = {0.f, 0.f, 0.f, 0.f};
        f32x4 acc1 = {0.f, 0.f, 0.f, 0.f};
        #pragma unroll
        for (int s = 0; s < 4; ++s) {
            bf16x8 a = *(const bf16x8*)&s_hn[l16][32 * s + 8 * quad];
            acc0 = __builtin_amdgcn_mfma_f32_16x16x32_bf16(a, bfrag[s][0], acc0, 0, 0, 0);
            acc1 = __builtin_amdgcn_mfma_f32_16x16x32_bf16(a, bfrag[s][1], acc1, 0, 0, 0);
        }
        #pragma unroll
        for (int r = 0; r < 4; ++r) {
            int row = quad * 4 + r;
            int vr = v0 + row;
            if (vr < n) {
                out[(size_t)vr * D + n0 + l16]      = acc0[r] + bias0;
                out[(size_t)vr * D + n0 + 16 + l16] = acc1[r] + bias1;
            }
        }
        __syncthreads();
    }
}

// ---------------- fallbacks ----------------
__global__ __launch_bounds__(128) void col_sum_kernel(const float* __restrict__ feat,
                                                      float* __restrict__ total, int n) {
    int d = threadIdx.x;
    float acc = 0.f;
    for (int r = blockIdx.x; r < n; r += gridDim.x)
        acc += feat[(size_t)r * D + d];
    atomAddF(&total[d], acc);
}

__global__ __launch_bounds__(256) void cvt_bf16_kernel(const float* __restrict__ feat,
                                                       bf16_t* __restrict__ featb,
                                                       long long n8) {
    long long i = (long long)blockIdx.x * 256 + threadIdx.x;
    if (i >= n8) return;
    const float4 a = *(const float4*)&feat[i * 8];
    const float4 b = *(const float4*)&feat[i * 8 + 4];
    bf16x8 o;
    o[0] = (bf16_t)a.x; o[1] = (bf16_t)a.y; o[2] = (bf16_t)a.z; o[3] = (bf16_t)a.w;
    o[4] = (bf16_t)b.x; o[5] = (bf16_t)b.y; o[6] = (bf16_t)b.z; o[7] = (bf16_t)b.w;
    *(bf16x8*)&featb[i * 8] = o;
}

__global__ __launch_bounds__(256) void fill_kernel(const int* __restrict__ src,
                                                   const int* __restrict__ dst,
                                                   int* __restrict__ cursor,
                                                   int* __restrict__ adj, int nE) {
    int e = blockIdx.x * 256 + threadIdx.x;
    if (e < nE) {
        int s = src[e], t = dst[e];
        int pos = atomicAdd(&cursor[t], 1);
        adj[pos] = s;
    }
}

__global__ __launch_bounds__(256) void scatter_kernel(const float* __restrict__ feat,
                                                      const int* __restrict__ src,
                                                      const int* __restrict__ dst,
                                                      float* __restrict__ neigh, int nE) {
    long long nwork = (long long)nE * 64;
    long long stride = (long long)gridDim.x * 256;
    for (long long i = (long long)blockIdx.x * 256 + threadIdx.x; i < nwork; i += stride) {
        int e = (int)(i >> 6);
        int d2 = (int)(i & 63) * 2;
        int s = src[e], t = dst[e];
        const float2 vv = *(const float2*)&feat[(size_t)s * D + d2];
        float* p = &neigh[(size_t)t * D + d2];
        atomAddF(p + 0, vv.x);
        atomAddF(p + 1, vv.y);
    }
}

__global__ __launch_bounds__(256) void finalize_kernel(const float* __restrict__ neigh,
                                                       const float* __restrict__ total,
                                                       const float* __restrict__ W,
                                                       const float* __restrict__ bias,
                                                       float* __restrict__ out,
                                                       int n, int ngroups) {
    __shared__ __hip_bfloat16 Wt[D * D];
    __shared__ __align__(16) float hnt[2][D][4];
    __shared__ float red[2][2][4];
    int tid = threadIdx.x;
    for (int idx = tid; idx < D * D; idx += 256) {
        int j = idx & 127, dd = idx >> 7;
        Wt[idx] = __float2bfloat16(W[(size_t)j * D + dd]);
    }
    int half = tid >> 7, d = tid & 127, wih = (tid >> 6) & 1, lane = tid & 63;
    float bj = bias[d], tot = total[d];
    __syncthreads();
    for (int g = blockIdx.x; g < ngroups; g += gridDim.x) {
        int nb = g * 8 + half * 4;
        float h0=0,h1=0,h2=0,h3=0;
        if (nb+0 < n) h0 = tot - neigh[(size_t)(nb+0)*D + d];
        if (nb+1 < n) h1 = tot - neigh[(size_t)(nb+1)*D + d];
        if (nb+2 < n) h2 = tot - neigh[(size_t)(nb+2)*D + d];
        if (nb+3 < n) h3 = tot - neigh[(size_t)(nb+3)*D + d];
        float s0=h0*h0,s1=h1*h1,s2=h2*h2,s3=h3*h3;
        #pragma unroll
        for (int off = 32; off > 0; off >>= 1) {
            s0 += __shfl_xor(s0, off, 64); s1 += __shfl_xor(s1, off, 64);
            s2 += __shfl_xor(s2, off, 64); s3 += __shfl_xor(s3, off, 64);
        }
        if (lane == 0) { red[half][wih][0]=s0; red[half][wih][1]=s1; red[half][wih][2]=s2; red[half][wih][3]=s3; }
        __syncthreads();
        float rinv[4];
        #pragma unroll
        for (int k = 0; k < 4; ++k)
            rinv[k] = 1.0f / fmaxf(sqrtf(red[half][0][k] + red[half][1][k]), 1e-12f);
        hnt[half][d][0]=h0*rinv[0]; hnt[half][d][1]=h1*rinv[1];
        hnt[half][d][2]=h2*rinv[2]; hnt[half][d][3]=h3*rinv[3];
        __syncthreads();
        float a0=0,a1=0,a2=0,a3=0;
        #pragma unroll 8
        for (int dd = 0; dd < D; ++dd) {
            float4 hn4 = *(const float4*)&hnt[half][dd][0];
            float wv = __bfloat162float(Wt[dd * D + d]);
            a0 = fmaf(hn4.x, wv, a0); a1 = fmaf(hn4.y, wv, a1);
            a2 = fmaf(hn4.z, wv, a2); a3 = fmaf(hn4.w, wv, a3);
        }
        if (nb+0 < n) out[(size_t)(nb+0)*D + d] = a0 + bj;
        if (nb+1 < n) out[(size_t)(nb+1)*D + d] = a1 + bj;
        if (nb+2 < n) out[(size_t)(nb+2)*D + d] = a2 + bj;
        if (nb+3 < n) out[(size_t)(nb+3)*D + d] = a3 + bj;
        __syncthreads();
    }
}

static inline size_t align_up(size_t x, size_t a) { return (x + a - 1) & ~(a - 1); }

extern "C" void kernel_launch(void* const* d_in, const int* in_sizes, int n_in,
                              void* d_out, int out_size, void* d_ws, size_t ws_size,
                              hipStream_t stream) {
    const float* feat = (const float*)d_in[0];
    const float* W    = (const float*)d_in[1];
    const float* bias = (const float*)d_in[2];
    const int*   src  = (const int*)d_in[3];
    const int*   dst  = (const int*)d_in[4];
    float* out = (float*)d_out;

    int n  = in_sizes[0] / D;   // 100000
    int nE = in_sizes[3];       // 1600000
    int NB = (n + 1023) / 1024; // buckets of 1024 nodes

    // ws layout
    char* wsb = (char*)d_ws;
    size_t o_total  = 0;
    size_t o_deg    = 512;
    size_t o_cur    = o_deg + (size_t)4 * n;
    size_t o_ptr    = o_cur + (size_t)4 * n;
    size_t o_bsum   = align_up(o_ptr + (size_t)4 * (n + 1), 512);
    size_t o_boff   = o_bsum + 1024;
    size_t o_bcur   = o_boff + 1024;
    size_t o_adj    = align_up(o_bcur + (size_t)4 * NB, 512);
    size_t o_packed = o_adj + (size_t)4 * nE;
    size_t o_featb  = align_up(o_packed + (size_t)4 * nE, 512);
    size_t needNew  = o_featb + (size_t)n * D * 2;
    size_t needOld  = o_packed;                      // old path: no packed
    size_t needOldB = o_featb + (size_t)n * D * 2;   // old fill + bf16 gather

    float*    total  = (float*)(wsb + o_total);
    int*      deg    = (int*)(wsb + o_deg);
    int*      cursor = (int*)(wsb + o_cur);
    int*      ptr    = (int*)(wsb + o_ptr);
    int*      bsum   = (int*)(wsb + o_bsum);
    int*      boff   = (int*)(wsb + o_boff);
    int*      bcur   = (int*)(wsb + o_bcur);
    int*      adj    = (int*)(wsb + o_adj);
    unsigned* packed = (unsigned*)(wsb + o_packed);
    bf16_t*   featb  = (bf16_t*)(wsb + o_featb);

    int eblocks = (nE + 255) / 256;
    int nb = (n + 1023) / 1024;
    long long n8 = (long long)n * (D / 8);
    int ngroups16 = (n + 15) / 16;
    int grid16 = ngroups16 < 2048 ? ngroups16 : 2048;

    bool packOK = (n <= (1 << 17)) && (NB <= 1024);

    if (ws_size >= needNew && packOK) {
        hipMemsetAsync(wsb, 0, o_cur, stream);  // zero total + deg
        cvt_colsum_kernel<<<512, 256, 0, stream>>>(feat, featb, total, n8);
        hist_kernel<<<eblocks, 256, 0, stream>>>(dst, deg, nE);
        scan_reduce_kernel<<<nb, 256, 0, stream>>>(deg, bsum, n);
        scan_bsum_kernel<<<1, 64, 0, stream>>>(bsum, boff, nb);
        scan_apply_kernel<<<nb, 256, 0, stream>>>(deg, boff, ptr, cursor, n);
        bcur_init_kernel<<<(NB + 255) / 256, 256, 0, stream>>>(ptr, bcur, NB, n);
        int chunk = (nE + 511) / 512;
        bucket_scatter_kernel<<<512, 256, 0, stream>>>(src, dst, bcur, packed, nE, NB, chunk);
        int nsub = 4;
        fill_local_kernel<<<NB * nsub, 256, 0, stream>>>(packed, ptr, cursor, adj, n, nsub);
        gather_mfma_kernel<<<grid16, 256, 0, stream>>>(featb, ptr, adj, total, W, bias,
                                                       out, n, ngroups16);
    } else if (ws_size >= needOldB) {
        hipMemsetAsync(wsb, 0, o_cur, stream);
        cvt_colsum_kernel<<<512, 256, 0, stream>>>(feat, featb, total, n8);
        hist_kernel<<<eblocks, 256, 0, stream>>>(dst, deg, nE);
        scan_reduce_kernel<<<nb, 256, 0, stream>>>(deg, bsum, n);
        scan_bsum_kernel<<<1, 64, 0, stream>>>(bsum, boff, nb);
        scan_apply_kernel<<<nb, 256, 0, stream>>>(deg, boff, ptr, cursor, n);
        fill_kernel<<<eblocks, 256, 0, stream>>>(src, dst, cursor, adj, nE);
        gather_mfma_kernel<<<grid16, 256, 0, stream>>>(featb, ptr, adj, total, W, bias,
                                                       out, n, ngroups16);
    } else {
        float* neigh = out;
        if (ws_size >= D * sizeof(float))
            hipMemsetAsync(d_ws, 0, D * sizeof(float), stream);
        hipMemsetAsync(neigh, 0, (size_t)out_size * sizeof(float), stream);
        col_sum_kernel<<<512, 128, 0, stream>>>(feat, total, n);
        scatter_kernel<<<16384, 256, 0, stream>>>(feat, src, dst, neigh, nE);
        int ngroups = (n + 7) / 8;
        finalize_kernel<<<2048, 256, 0, stream>>>(neigh, total, W, bias, out, n, ngroups);
    }
}

// Round 7
// 254.255 us; speedup vs baseline: 6.3494x; 1.4263x over previous
//
#include <hip/hip_runtime.h>
#include <hip/hip_bf16.h>

#define D 128

typedef __bf16 bf16_t;
typedef bf16_t bf16x8 __attribute__((ext_vector_type(8)));
typedef float  f32x4  __attribute__((ext_vector_type(4)));

__device__ __forceinline__ void atomAddF(float* p, float v) {
    unsafeAtomicAdd(p, v);
}

// ---------------- fused: fp32->bf16 staging + column totals ----------------
__global__ __launch_bounds__(256) void cvt_colsum_kernel(const float* __restrict__ feat,
                                                         bf16_t* __restrict__ featb,
                                                         float* __restrict__ total,
                                                         long long n8) {
    __shared__ float red[4][16][8];
    int tid = threadIdx.x, lane = tid & 63, w = tid >> 6;
    long long G = (long long)gridDim.x * 256;
    float acc[8];
    #pragma unroll
    for (int e = 0; e < 8; ++e) acc[e] = 0.f;
    for (long long i = (long long)blockIdx.x * 256 + tid; i < n8; i += G) {
        const float4 a = *(const float4*)&feat[i * 8];
        const float4 b = *(const float4*)&feat[i * 8 + 4];
        bf16x8 o;
        o[0] = (bf16_t)a.x; o[1] = (bf16_t)a.y; o[2] = (bf16_t)a.z; o[3] = (bf16_t)a.w;
        o[4] = (bf16_t)b.x; o[5] = (bf16_t)b.y; o[6] = (bf16_t)b.z; o[7] = (bf16_t)b.w;
        *(bf16x8*)&featb[i * 8] = o;
        acc[0] += a.x; acc[1] += a.y; acc[2] += a.z; acc[3] += a.w;
        acc[4] += b.x; acc[5] += b.y; acc[6] += b.z; acc[7] += b.w;
    }
    #pragma unroll
    for (int e = 0; e < 8; ++e) {
        acc[e] += __shfl_xor(acc[e], 16, 64);
        acc[e] += __shfl_xor(acc[e], 32, 64);
    }
    if (lane < 16) {
        #pragma unroll
        for (int e = 0; e < 8; ++e) red[w][lane][e] = acc[e];
    }
    __syncthreads();
    if (tid < 128) {
        int cb = tid >> 3, e = tid & 7;
        float s = red[0][cb][e] + red[1][cb][e] + red[2][cb][e] + red[3][cb][e];
        atomAddF(&total[cb * 8 + e], s);
    }
}

// ---------------- bucket-level CSR build (256-node buckets, no per-edge global atomics) ----
__global__ __launch_bounds__(256) void bucket_count_kernel(const int* __restrict__ dst,
                                                           int* __restrict__ bcount,
                                                           int nE, int NB, int chunk) {
    __shared__ int hist[1024];
    int tid = threadIdx.x;
    int c0 = blockIdx.x * chunk;
    int c1 = c0 + chunk; if (c1 > nE) c1 = nE;
    for (int i = tid; i < NB; i += 256) hist[i] = 0;
    __syncthreads();
    for (int i = c0 + tid; i < c1; i += 256) atomicAdd(&hist[dst[i] >> 8], 1);
    __syncthreads();
    for (int i = tid; i < NB; i += 256) {
        int h = hist[i];
        if (h) atomicAdd(&bcount[i], h);
    }
}

// single block, 1024 threads: exclusive scan of bcount[0..NB) -> bbase[0..NB], bcur init
__global__ __launch_bounds__(1024) void bscan_kernel(const int* __restrict__ bcount,
                                                     int* __restrict__ bbase,
                                                     int* __restrict__ bcur,
                                                     int NB, int nE) {
    int tid = threadIdx.x, lane = tid & 63, w = tid >> 6;
    int v = (tid < NB) ? bcount[tid] : 0;
    int x = v;
    #pragma unroll
    for (int off = 1; off < 64; off <<= 1) {
        int y = __shfl_up(x, off, 64);
        if (lane >= off) x += y;
    }
    __shared__ int ws[16];
    if (lane == 63) ws[w] = x;
    __syncthreads();
    if (w == 0 && lane < 16) {
        int s = ws[lane];
        #pragma unroll
        for (int off = 1; off < 16; off <<= 1) {
            int y = __shfl_up(s, off, 64);
            if (lane >= off) s += y;
        }
        ws[lane] = s;
    }
    __syncthreads();
    int base = (w == 0) ? 0 : ws[w - 1];
    int excl = base + x - v;
    if (tid < NB) { bbase[tid] = excl; bcur[tid] = excl; }
    if (tid == 0) bbase[NB] = nE;
}

// per-block LDS hist -> run reservation -> dense packed scatter
// packed: bits 0..16 = src (n < 2^17), bits 17..24 = dst & 255
__global__ __launch_bounds__(256) void bucket_scatter_kernel(const int* __restrict__ src,
                                                             const int* __restrict__ dst,
                                                             int* __restrict__ bcur,
                                                             unsigned* __restrict__ packed,
                                                             int nE, int NB, int chunk) {
    __shared__ int hist[1024];
    __shared__ int cur[1024];
    int tid = threadIdx.x;
    int c0 = blockIdx.x * chunk;
    int c1 = c0 + chunk; if (c1 > nE) c1 = nE;
    for (int i = tid; i < NB; i += 256) hist[i] = 0;
    __syncthreads();
    for (int i = c0 + tid; i < c1; i += 256) atomicAdd(&hist[dst[i] >> 8], 1);
    __syncthreads();
    for (int i = tid; i < NB; i += 256) {
        int h = hist[i];
        cur[i] = h ? atomicAdd(&bcur[i], h) : 0;
    }
    __syncthreads();
    for (int i = c0 + tid; i < c1; i += 256) {
        int t = dst[i];
        int b = t >> 8;
        int off = atomicAdd(&cur[b], 1);
        packed[off] = ((unsigned)(t & 255) << 17) | (unsigned)src[i];
    }
}

// one block per bucket: LDS hist -> LDS scan -> ptr write -> LDS-cursor scatter to adj
__global__ __launch_bounds__(256) void fill_sort_kernel(const unsigned* __restrict__ packed,
                                                        const int* __restrict__ bbase,
                                                        int* __restrict__ ptr,
                                                        int* __restrict__ adj,
                                                        int n, int NB, int nE) {
    __shared__ int cnt[256];
    __shared__ int lcur[256];
    __shared__ int wsum[4];
    int b = blockIdx.x;
    int tid = threadIdx.x, lane = tid & 63, w = tid >> 6;
    int base = bbase[b], end = bbase[b + 1];
    cnt[tid] = 0;
    __syncthreads();
    for (int i = base + tid; i < end; i += 256)
        atomicAdd(&cnt[packed[i] >> 17], 1);
    __syncthreads();
    int v = cnt[tid];
    int x = v;
    #pragma unroll
    for (int off = 1; off < 64; off <<= 1) {
        int y = __shfl_up(x, off, 64);
        if (lane >= off) x += y;
    }
    if (lane == 63) wsum[w] = x;
    __syncthreads();
    int wb = 0;
    for (int k = 0; k < w; ++k) wb += wsum[k];
    int excl = wb + x - v;
    int start = base + excl;
    lcur[tid] = start;
    int node = b * 256 + tid;
    if (node < n) ptr[node] = start;
    if (b == NB - 1 && tid == 0) ptr[n] = nE;
    __syncthreads();
    for (int i = base + tid; i < end; i += 256) {
        unsigned pv = packed[i];
        int j = (int)(pv >> 17);
        int pos = atomicAdd(&lcur[j], 1);   // LDS atomic
        adj[pos] = (int)(pv & 0x1FFFFu);
    }
}

// ---- fused: CSR gather (bf16, wide loads, LDS-staged indices) + normalize + MFMA ----
__global__ __launch_bounds__(256, 4) void gather_mfma_kernel(const bf16_t* __restrict__ featb,
                                                             const int* __restrict__ ptr,
                                                             const int* __restrict__ adj,
                                                             const float* __restrict__ total,
                                                             const float* __restrict__ W,
                                                             const float* __restrict__ bias,
                                                             float* __restrict__ out,
                                                             int n, int ngroups) {
    __shared__ int    s_adj[1024];
    __shared__ bf16_t s_hn[16][136];

    int tid  = threadIdx.x;
    int lane = tid & 63;
    int w    = tid >> 6;
    int quad = lane >> 4;
    int l16  = lane & 15;

    int n0 = w * 32;
    bf16x8 bfrag[4][2];
    #pragma unroll
    for (int s = 0; s < 4; ++s)
        #pragma unroll
        for (int c = 0; c < 2; ++c) {
            const float* wp = W + (size_t)(n0 + 16 * c + l16) * D + 32 * s + 8 * quad;
            float4 wa = *(const float4*)wp;
            float4 wb = *(const float4*)(wp + 4);
            bf16x8 bf;
            bf[0] = (bf16_t)wa.x; bf[1] = (bf16_t)wa.y; bf[2] = (bf16_t)wa.z; bf[3] = (bf16_t)wa.w;
            bf[4] = (bf16_t)wb.x; bf[5] = (bf16_t)wb.y; bf[6] = (bf16_t)wb.z; bf[7] = (bf16_t)wb.w;
            bfrag[s][c] = bf;
        }
    float bias0 = bias[n0 + l16];
    float bias1 = bias[n0 + 16 + l16];

    int k_node = tid >> 4;
    int d8 = (tid & 15) * 8;
    float tot8[8];
    {
        float4 ta = *(const float4*)&total[d8];
        float4 tb = *(const float4*)&total[d8 + 4];
        tot8[0] = ta.x; tot8[1] = ta.y; tot8[2] = ta.z; tot8[3] = ta.w;
        tot8[4] = tb.x; tot8[5] = tb.y; tot8[6] = tb.z; tot8[7] = tb.w;
    }

    for (int g = blockIdx.x; g < ngroups; g += gridDim.x) {
        int v0 = g * 16;
        int v  = v0 + k_node;
        bool valid = v < n;
        int p0 = valid ? ptr[v] : 0;
        int p1 = valid ? ptr[v + 1] : 0;
        int vend = v0 + 16 < n ? v0 + 16 : n;
        int P0 = ptr[v0];
        int P1 = ptr[vend];

        float acc8[8];
        #pragma unroll
        for (int e = 0; e < 8; ++e) acc8[e] = 0.f;

        for (int base = P0; base < P1; base += 1024) {
            int cnt = P1 - base; if (cnt > 1024) cnt = 1024;
            __syncthreads();
            for (int i = tid; i < cnt; i += 256) s_adj[i] = adj[base + i];
            __syncthreads();
            int lo = p0 > base ? p0 : base;
            int hi = p1 < base + cnt ? p1 : base + cnt;
            int p = lo;
            for (; p + 3 < hi; p += 4) {
                int s0 = s_adj[p - base],     s1 = s_adj[p - base + 1];
                int s2 = s_adj[p - base + 2], s3 = s_adj[p - base + 3];
                bf16x8 f0 = *(const bf16x8*)(featb + (size_t)s0 * D + d8);
                bf16x8 f1 = *(const bf16x8*)(featb + (size_t)s1 * D + d8);
                bf16x8 f2 = *(const bf16x8*)(featb + (size_t)s2 * D + d8);
                bf16x8 f3 = *(const bf16x8*)(featb + (size_t)s3 * D + d8);
                #pragma unroll
                for (int e = 0; e < 8; ++e)
                    acc8[e] += ((float)f0[e] + (float)f1[e]) + ((float)f2[e] + (float)f3[e]);
            }
            for (; p < hi; ++p) {
                int s0 = s_adj[p - base];
                bf16x8 f0 = *(const bf16x8*)(featb + (size_t)s0 * D + d8);
                #pragma unroll
                for (int e = 0; e < 8; ++e) acc8[e] += (float)f0[e];
            }
        }

        float h8[8], ss = 0.f;
        #pragma unroll
        for (int e = 0; e < 8; ++e) {
            h8[e] = valid ? (tot8[e] - acc8[e]) : 0.f;
            ss = fmaf(h8[e], h8[e], ss);
        }
        ss += __shfl_xor(ss, 1, 64);
        ss += __shfl_xor(ss, 2, 64);
        ss += __shfl_xor(ss, 4, 64);
        ss += __shfl_xor(ss, 8, 64);
        float rinv = 1.0f / fmaxf(sqrtf(ss), 1e-12f);

        bf16x8 hv;
        #pragma unroll
        for (int e = 0; e < 8; ++e) hv[e] = (bf16_t)(h8[e] * rinv);
        *(bf16x8*)&s_hn[k_node][d8] = hv;
        __syncthreads();

        f32x4 acc0 = {0.f, 0.f, 0.f, 0.f};
        f32x4 acc1 = {0.f, 0.f, 0.f, 0.f};
        #pragma unroll
        for (int s = 0; s < 4; ++s) {
            bf16x8 a = *(const bf16x8*)&s_hn[l16][32 * s + 8 * quad];
            acc0 = __builtin_amdgcn_mfma_f32_16x16x32_bf16(a, bfrag[s][0], acc0, 0, 0, 0);
            acc1 = __builtin_amdgcn_mfma_f32_16x16x32_bf16(a, bfrag[s][1], acc1, 0, 0, 0);
        }
        #pragma unroll
        for (int r = 0; r < 4; ++r) {
            int row = quad * 4 + r;
            int vr = v0 + row;
            if (vr < n) {
                out[(size_t)vr * D + n0 + l16]      = acc0[r] + bias0;
                out[(size_t)vr * D + n0 + 16 + l16] = acc1[r] + bias1;
            }
        }
        __syncthreads();
    }
}

// ---------------- fallback: round-3 atomic scatter path ----------------
__global__ __launch_bounds__(128) void col_sum_kernel(const float* __restrict__ feat,
                                                      float* __restrict__ total, int n) {
    int d = threadIdx.x;
    float acc = 0.f;
    for (int r = blockIdx.x; r < n; r += gridDim.x)
        acc += feat[(size_t)r * D + d];
    atomAddF(&total[d], acc);
}

__global__ __launch_bounds__(256) void scatter_kernel(const float* __restrict__ feat,
                                                      const int* __restrict__ src,
                                                      const int* __restrict__ dst,
                                                      float* __restrict__ neigh, int nE) {
    long long nwork = (long long)nE * 64;
    long long stride = (long long)gridDim.x * 256;
    for (long long i = (long long)blockIdx.x * 256 + threadIdx.x; i < nwork; i += stride) {
        int e = (int)(i >> 6);
        int d2 = (int)(i & 63) * 2;
        int s = src[e], t = dst[e];
        const float2 vv = *(const float2*)&feat[(size_t)s * D + d2];
        float* p = &neigh[(size_t)t * D + d2];
        atomAddF(p + 0, vv.x);
        atomAddF(p + 1, vv.y);
    }
}

__global__ __launch_bounds__(256) void finalize_kernel(const float* __restrict__ neigh,
                                                       const float* __restrict__ total,
                                                       const float* __restrict__ W,
                                                       const float* __restrict__ bias,
                                                       float* __restrict__ out,
                                                       int n, int ngroups) {
    __shared__ __hip_bfloat16 Wt[D * D];
    __shared__ __align__(16) float hnt[2][D][4];
    __shared__ float red[2][2][4];
    int tid = threadIdx.x;
    for (int idx = tid; idx < D * D; idx += 256) {
        int j = idx & 127, dd = idx >> 7;
        Wt[idx] = __float2bfloat16(W[(size_t)j * D + dd]);
    }
    int half = tid >> 7, d = tid & 127, wih = (tid >> 6) & 1, lane = tid & 63;
    float bj = bias[d], tot = total[d];
    __syncthreads();
    for (int g = blockIdx.x; g < ngroups; g += gridDim.x) {
        int nb = g * 8 + half * 4;
        float h0=0,h1=0,h2=0,h3=0;
        if (nb+0 < n) h0 = tot - neigh[(size_t)(nb+0)*D + d];
        if (nb+1 < n) h1 = tot - neigh[(size_t)(nb+1)*D + d];
        if (nb+2 < n) h2 = tot - neigh[(size_t)(nb+2)*D + d];
        if (nb+3 < n) h3 = tot - neigh[(size_t)(nb+3)*D + d];
        float s0=h0*h0,s1=h1*h1,s2=h2*h2,s3=h3*h3;
        #pragma unroll
        for (int off = 32; off > 0; off >>= 1) {
            s0 += __shfl_xor(s0, off, 64); s1 += __shfl_xor(s1, off, 64);
            s2 += __shfl_xor(s2, off, 64); s3 += __shfl_xor(s3, off, 64);
        }
        if (lane == 0) { red[half][wih][0]=s0; red[half][wih][1]=s1; red[half][wih][2]=s2; red[half][wih][3]=s3; }
        __syncthreads();
        float rinv[4];
        #pragma unroll
        for (int k = 0; k < 4; ++k)
            rinv[k] = 1.0f / fmaxf(sqrtf(red[half][0][k] + red[half][1][k]), 1e-12f);
        hnt[half][d][0]=h0*rinv[0]; hnt[half][d][1]=h1*rinv[1];
        hnt[half][d][2]=h2*rinv[2]; hnt[half][d][3]=h3*rinv[3];
        __syncthreads();
        float a0=0,a1=0,a2=0,a3=0;
        #pragma unroll 8
        for (int dd = 0; dd < D; ++dd) {
            float4 hn4 = *(const float4*)&hnt[half][dd][0];
            float wv = __bfloat162float(Wt[dd * D + d]);
            a0 = fmaf(hn4.x, wv, a0); a1 = fmaf(hn4.y, wv, a1);
            a2 = fmaf(hn4.z, wv, a2); a3 = fmaf(hn4.w, wv, a3);
        }
        if (nb+0 < n) out[(size_t)(nb+0)*D + d] = a0 + bj;
        if (nb+1 < n) out[(size_t)(nb+1)*D + d] = a1 + bj;
        if (nb+2 < n) out[(size_t)(nb+2)*D + d] = a2 + bj;
        if (nb+3 < n) out[(size_t)(nb+3)*D + d] = a3 + bj;
        __syncthreads();
    }
}

static inline size_t align_up(size_t x, size_t a) { return (x + a - 1) & ~(a - 1); }

extern "C" void kernel_launch(void* const* d_in, const int* in_sizes, int n_in,
                              void* d_out, int out_size, void* d_ws, size_t ws_size,
                              hipStream_t stream) {
    const float* feat = (const float*)d_in[0];
    const float* W    = (const float*)d_in[1];
    const float* bias = (const float*)d_in[2];
    const int*   src  = (const int*)d_in[3];
    const int*   dst  = (const int*)d_in[4];
    float* out = (float*)d_out;

    int n  = in_sizes[0] / D;   // 100000
    int nE = in_sizes[3];       // 1600000
    int NB = (n + 255) / 256;   // 256-node buckets (391)

    // ws layout: [total 512][bcount 4K][bbase 4.5K][bcur 4K][ptr 4(n+1)][adj 4nE][packed 4nE][featb 2nD]
    char* wsb = (char*)d_ws;
    size_t o_total  = 0;
    size_t o_bcount = 512;
    size_t o_bbase  = o_bcount + 4096;
    size_t o_bcur   = o_bbase + 4608;
    size_t o_ptr    = o_bcur + 4096;
    size_t o_adj    = align_up(o_ptr + (size_t)4 * (n + 1), 512);
    size_t o_packed = o_adj + (size_t)4 * nE;
    size_t o_featb  = align_up(o_packed + (size_t)4 * nE, 512);
    size_t needNew  = o_featb + (size_t)n * D * 2;

    float*    total  = (float*)(wsb + o_total);
    int*      bcount = (int*)(wsb + o_bcount);
    int*      bbase  = (int*)(wsb + o_bbase);
    int*      bcur   = (int*)(wsb + o_bcur);
    int*      ptr    = (int*)(wsb + o_ptr);
    int*      adj    = (int*)(wsb + o_adj);
    unsigned* packed = (unsigned*)(wsb + o_packed);
    bf16_t*   featb  = (bf16_t*)(wsb + o_featb);

    long long n8 = (long long)n * (D / 8);
    int ngroups16 = (n + 15) / 16;
    int grid16 = ngroups16 < 2048 ? ngroups16 : 2048;

    bool packOK = (n <= (1 << 17)) && (NB <= 1024);

    if (ws_size >= needNew && packOK) {
        hipMemsetAsync(wsb, 0, o_bbase, stream);   // zero total + bcount
        cvt_colsum_kernel<<<512, 256, 0, stream>>>(feat, featb, total, n8);
        int chunk = (nE + 511) / 512;
        bucket_count_kernel<<<512, 256, 0, stream>>>(dst, bcount, nE, NB, chunk);
        bscan_kernel<<<1, 1024, 0, stream>>>(bcount, bbase, bcur, NB, nE);
        bucket_scatter_kernel<<<512, 256, 0, stream>>>(src, dst, bcur, packed, nE, NB, chunk);
        fill_sort_kernel<<<NB, 256, 0, stream>>>(packed, bbase, ptr, adj, n, NB, nE);
        gather_mfma_kernel<<<grid16, 256, 0, stream>>>(featb, ptr, adj, total, W, bias,
                                                       out, n, ngroups16);
    } else {
        float* neigh = out;
        if (ws_size >= D * sizeof(float))
            hipMemsetAsync(d_ws, 0, D * sizeof(float), stream);
        hipMemsetAsync(neigh, 0, (size_t)out_size * sizeof(float), stream);
        col_sum_kernel<<<512, 128, 0, stream>>>(feat, total, n);
        scatter_kernel<<<16384, 256, 0, stream>>>(feat, src, dst, neigh, nE);
        int ngroups = (n + 7) / 8;
        finalize_kernel<<<2048, 256, 0, stream>>>(neigh, total, W, bias, out, n, ngroups);
    }
}